// Round 20
// baseline (144.427 us; speedup 1.0000x reference)
//
#include <hip/hip_runtime.h>
#include <hip/hip_bf16.h>

// HPBC step — geometry SOLVED (R18/R19: Output 0 passes):
//   * Inputs dict order, f32, TRUE complex assembly (E = E_real + 1j*E_imag).
//   * Output buffer = [E'-chunk | Eo-chunk], each out_size=2,093,952 bf16;
//     element storage is (IMAG, REAL) per (b, i', pol)  [alphabetical
//     {imag, real} stacking on the OUTPUT side -- proven by chunk 0].
//   * nout = 65,436, lpad = 50.
// Compute: factored form  Eo = F + P^1.5 * Σ_m [FIR_n(c1·G_m + c2·H_m)]·E(i-m),
//   G_m[j] = Σ_p E[j,p]conj(F[j-m,p]),  H_m[j] = Σ_p F[j,p]conj(E[j-m,p]).

namespace {

constexpr int NSEQ   = 65536;
constexpr int BATCH  = 8;
constexpr int KTAPS  = 449;
constexpr int NM     = 25;                       // max |m|, |n|
constexpr int TILE   = 256;
constexpr int WIN    = TILE + 4 * NM;            // 356  (E/F window, halo ±50)
constexpr int GHW    = TILE + 2 * NM;            // 306  (G/H window, halo ±25)

__device__ inline unsigned short f2bf(float f) {
  __hip_bfloat16 h = __float2bfloat16(f);
  union { __hip_bfloat16 hh; unsigned short u; } cv;
  cv.hh = h;
  return cv.u;
}

// cw[row*K + k] = (c1r, c1i, c2r, c2i)  -- true complex C tables.
__global__ void prep_c_kernel(const float* __restrict__ c1r, const float* __restrict__ c1i,
                              const float* __restrict__ c2r, const float* __restrict__ c2i,
                              float4* __restrict__ cw) {
  int idx = blockIdx.x * blockDim.x + threadIdx.x;
  if (idx < 4 * KTAPS) cw[idx] = make_float4(c1r[idx], c1i[idx], c2r[idx], c2i[idx]);
}

__global__ __launch_bounds__(TILE) void hpbc_kernel(
    const float2* __restrict__ er, const float2* __restrict__ ei,
    const float2* __restrict__ fr, const float2* __restrict__ fi,
    const float*  __restrict__ task, const float4* __restrict__ cw,
    unsigned short* __restrict__ out, int nout, int lpad, int ntiles)
{
  __shared__ float4 sE[WIN];   // (p0.re, p0.im, p1.re, p1.im) per seq position
  __shared__ float4 sF[WIN];
  __shared__ float4 sGH[GHW];  // (Gr, Gi, Hr, Hi)

  const int bx   = blockIdx.x;
  const int b    = bx / ntiles;
  const int tile = bx - b * ntiles;
  const int tid  = threadIdx.x;
  const int i0   = lpad + tile * TILE;   // first output seq index of this tile
  const int elo  = i0 - 2 * NM;          // seq index of sE[0]/sF[0]

  const float2* erb = er + (size_t)b * NSEQ;
  const float2* eib = ei + (size_t)b * NSEQ;
  const float2* frb = fr + (size_t)b * NSEQ;
  const float2* fib = fi + (size_t)b * NSEQ;

  // Stage E/F windows with exact jnp.roll (modular) semantics.
  for (int u = tid; u < WIN; u += TILE) {
    int g = (elo + u) & (NSEQ - 1);
    float2 a = erb[g], c = eib[g];
    sE[u] = make_float4(a.x, c.x, a.y, c.y);
    float2 d = frb[g], e = fib[g];
    sF[u] = make_float4(d.x, e.x, d.y, e.y);
  }

  // Per-batch params (uniform within block).
  const float dbm = task[b * 4 + 0];
  const float fsr = task[b * 4 + 2];
  const int   x   = (int)(fsr / 2.0e9f);
  // rs_sorted = {20,40,80,160}; ind = argmax(x == rs_sorted) -> first match, else 0
  const int ind = (x == 40) ? 1 : (x == 80) ? 2 : (x == 160) ? 3 : 0;
  const float4* __restrict__ crow = cw + ind * KTAPS;
  const float P  = powf(10.0f, dbm * 0.1f) * 0.5f;  // 10^(dBm/10) / M, M=2
  const float pf = P * sqrtf(P);                    // (sqrt(P))^3

  __syncthreads();

  // Hoist unshifted E[j], F[j] for this thread's gh positions.
  const float4 e_a = sE[tid + NM];
  const float4 f_a = sF[tid + NM];
  const bool  has2 = (tid < GHW - TILE);   // tid < 50
  float4 e_b = make_float4(0.f, 0.f, 0.f, 0.f), f_b = e_b;
  if (has2) { e_b = sE[tid + TILE + NM]; f_b = sF[tid + TILE + NM]; }

  float a0r = 0.f, a0i = 0.f, a1r = 0.f, a1i = 0.f;
  int kbase = 0;

  for (int mm = -NM; mm <= NM; ++mm) {
    // ---- G/H phase: sGH[j'] for j' in [0, GHW), seq pos j = (i0-25) + j' ----
    {
      const float4 fm = sF[tid + NM - mm];   // F[j-m]
      const float4 em = sE[tid + NM - mm];   // E[j-m]
      float Gr = e_a.x * fm.x + e_a.y * fm.y + e_a.z * fm.z + e_a.w * fm.w;
      float Gi = e_a.y * fm.x - e_a.x * fm.y + e_a.w * fm.z - e_a.z * fm.w;
      float Hr = f_a.x * em.x + f_a.y * em.y + f_a.z * em.z + f_a.w * em.w;
      float Hi = f_a.y * em.x - f_a.x * em.y + f_a.w * em.z - f_a.z * em.w;
      sGH[tid] = make_float4(Gr, Gi, Hr, Hi);
      if (has2) {
        const float4 fm2 = sF[tid + TILE + NM - mm];
        const float4 em2 = sE[tid + TILE + NM - mm];
        float Gr2 = e_b.x * fm2.x + e_b.y * fm2.y + e_b.z * fm2.z + e_b.w * fm2.w;
        float Gi2 = e_b.y * fm2.x - e_b.x * fm2.y + e_b.w * fm2.z - e_b.z * fm2.w;
        float Hr2 = f_b.x * em2.x + f_b.y * em2.y + f_b.z * em2.z + f_b.w * em2.w;
        float Hi2 = f_b.y * em2.x - f_b.x * em2.y + f_b.w * em2.z - f_b.z * em2.w;
        sGH[tid + TILE] = make_float4(Gr2, Gi2, Hr2, Hi2);
      }
    }
    __syncthreads();

    // ---- FIR taps for this m: sum over n in [-nmax, nmax] ----
    const int am   = mm < 0 ? -mm : mm;
    const int nmax = (mm == 0) ? NM : (NM / am);
    const int T    = 2 * nmax + 1;
    float u1 = 0.f, u2 = 0.f, u3 = 0.f, u4 = 0.f;
    float v1 = 0.f, v2 = 0.f, v3 = 0.f, v4 = 0.f;
    const int gb = tid + NM + nmax;   // sGH index for tap t: gb - t  (n = t - nmax)
    for (int t = 0; t < T; ++t) {
      const float4 gh = sGH[gb - t];
      const float4 c  = crow[kbase + t];   // uniform address -> scalar load
      u1 += c.x * gh.x; u2 += c.y * gh.y; u3 += c.x * gh.y; u4 += c.y * gh.x;
      v1 += c.z * gh.z; v2 += c.w * gh.w; v3 += c.z * gh.w; v4 += c.w * gh.z;
    }
    kbase += T;
    const float sr = u1 - u2 + v1 - v2;   // Re(c1*G + c2*H) summed over taps
    const float si = u3 + u4 + v3 + v4;   // Im
    const float4 eim = sE[tid + 2 * NM - mm];   // E[i-m]
    a0r += sr * eim.x - si * eim.y;
    a0i += sr * eim.y + si * eim.x;
    a1r += sr * eim.z - si * eim.w;
    a1i += sr * eim.w + si * eim.z;
    __syncthreads();   // before next m overwrites sGH
  }

  const int i = i0 + tid;
  if (i < lpad + nout) {
    const float4 ev = sE[tid + 2 * NM];   // E[i] = (re0, im0, re1, im1)
    const float4 fv = sF[tid + 2 * NM];   // F[i]
    // OUTPUT storage: (IMAG, REAL) per (b, i', pol) -- proven by chunk 0.
    // chunk0 = E' at [0, 32*nout); chunk1 = Eo at [32*nout, 64*nout).
    const size_t o0 = ((size_t)b * nout + (size_t)(i - lpad)) * 4;
    const size_t o1 = (size_t)BATCH * nout * 4 + o0;
    ushort4 w0, w1;
    w0.x = f2bf(ev.y);              // E' p0 imag
    w0.y = f2bf(ev.x);              // E' p0 real
    w0.z = f2bf(ev.w);              // E' p1 imag
    w0.w = f2bf(ev.z);              // E' p1 real
    w1.x = f2bf(fv.y + pf * a0i);   // Eo p0 imag
    w1.y = f2bf(fv.x + pf * a0r);   // Eo p0 real
    w1.z = f2bf(fv.w + pf * a1i);   // Eo p1 imag
    w1.w = f2bf(fv.z + pf * a1r);   // Eo p1 real
    *reinterpret_cast<ushort4*>(out + o0) = w0;
    *reinterpret_cast<ushort4*>(out + o1) = w1;
  }
}

} // namespace

extern "C" void kernel_launch(void* const* d_in, const int* in_sizes, int n_in,
                              void* d_out, int out_size, void* d_ws, size_t ws_size,
                              hipStream_t stream) {
  // Dict order (probe-confirmed), TRUE complex assembly (R19 killed the swap).
  const float* E_real  = (const float*)d_in[0];
  const float* E_imag  = (const float*)d_in[1];
  const float* F_real  = (const float*)d_in[2];
  const float* F_imag  = (const float*)d_in[3];
  const float* C1_real = (const float*)d_in[4];
  const float* C1_imag = (const float*)d_in[5];
  const float* C2_real = (const float*)d_in[6];
  const float* C2_imag = (const float*)d_in[7];
  const float* task    = (const float*)d_in[8];

  // out_size = per-output component count = 32 * nout.
  int nout = out_size / 32;
  if (nout < 1 || nout > NSEQ) nout = NSEQ - 100;
  const int lpad   = (NSEQ - nout) / 2;            // 50
  const int ntiles = (nout + TILE - 1) / TILE;     // 256

  unsigned short* outp = (unsigned short*)d_out;
  float4* cw = (float4*)d_ws;   // 4*449*16 = 28736 B of scratch

  hipLaunchKernelGGL(prep_c_kernel, dim3((4 * KTAPS + 255) / 256), dim3(256), 0, stream,
                     C1_real, C1_imag, C2_real, C2_imag, cw);

  hipLaunchKernelGGL(hpbc_kernel, dim3(BATCH * ntiles), dim3(TILE), 0, stream,
                     (const float2*)E_real, (const float2*)E_imag,
                     (const float2*)F_real, (const float2*)F_imag,
                     task, cw, outp, nout, lpad, ntiles);
}

// Round 21
// 104.969 us; speedup vs baseline: 1.3759x; 1.3759x over previous
//
#include <hip/hip_runtime.h>
#include <hip/hip_bf16.h>

// HPBC step — R=2 blocked, single-barrier double-buffered sGH.
// Geometry (solved): dict inputs, true complex assembly; output chunks
// [E' | Eo], element storage (IMAG, REAL) per (b, i', pol); nout=65436.
// Factored compute: Eo = F + P^1.5 * Σ_m [FIR_n(c1·G_m + c2·H_m)]·E(i-m).

namespace {

constexpr int NSEQ    = 65536;
constexpr int BATCH   = 8;
constexpr int KTAPS   = 449;
constexpr int NM      = 25;                      // max |m|, |n|
constexpr int THREADS = 256;
constexpr int TILE    = 512;                     // outputs per block (R=2/thread)
constexpr int WIN     = TILE + 4 * NM;           // 612  (E/F window, halo ±50)
constexpr int GHW     = TILE + 2 * NM;           // 562  (G/H window, halo ±25)

__device__ inline unsigned short f2bf(float f) {
  __hip_bfloat16 h = __float2bfloat16(f);
  union { __hip_bfloat16 hh; unsigned short u; } cv;
  cv.hh = h;
  return cv.u;
}

// cw[row*K + k] = (c1r, c1i, c2r, c2i)
__global__ void prep_c_kernel(const float* __restrict__ c1r, const float* __restrict__ c1i,
                              const float* __restrict__ c2r, const float* __restrict__ c2i,
                              float4* __restrict__ cw) {
  int idx = blockIdx.x * blockDim.x + threadIdx.x;
  if (idx < 4 * KTAPS) cw[idx] = make_float4(c1r[idx], c1i[idx], c2r[idx], c2i[idx]);
}

__global__ __launch_bounds__(THREADS) void hpbc_kernel(
    const float2* __restrict__ er, const float2* __restrict__ ei,
    const float2* __restrict__ fr, const float2* __restrict__ fi,
    const float*  __restrict__ task, const float4* __restrict__ cw,
    unsigned short* __restrict__ out, int nout, int lpad, int ntiles)
{
  __shared__ float4 sE[WIN];      // (p0.re, p0.im, p1.re, p1.im)
  __shared__ float4 sF[WIN];
  __shared__ float4 sGH[2][GHW];  // double-buffered (Gr, Gi, Hr, Hi)

  const int bx   = blockIdx.x;
  const int b    = bx / ntiles;
  const int tile = bx - b * ntiles;
  const int tid  = threadIdx.x;
  const int i0   = lpad + tile * TILE;   // first output seq index of this tile
  const int elo  = i0 - 2 * NM;

  const float2* erb = er + (size_t)b * NSEQ;
  const float2* eib = ei + (size_t)b * NSEQ;
  const float2* frb = fr + (size_t)b * NSEQ;
  const float2* fib = fi + (size_t)b * NSEQ;

  for (int u = tid; u < WIN; u += THREADS) {
    int g = (elo + u) & (NSEQ - 1);                  // exact jnp.roll wrap
    float2 a = erb[g], c = eib[g];
    sE[u] = make_float4(a.x, c.x, a.y, c.y);
    float2 d = frb[g], e = fib[g];
    sF[u] = make_float4(d.x, e.x, d.y, e.y);
  }

  const float dbm = task[b * 4 + 0];
  const float fsr = task[b * 4 + 2];
  const int   x   = (int)(fsr / 2.0e9f);
  const int ind = (x == 40) ? 1 : (x == 80) ? 2 : (x == 160) ? 3 : 0;
  const float4* __restrict__ crow = cw + ind * KTAPS;
  const float P  = powf(10.0f, dbm * 0.1f) * 0.5f;
  const float pf = P * sqrtf(P);

  __syncthreads();

  // Hoist unshifted E[j], F[j] for this thread's gh entries (u = tid, tid+256, tid+512).
  const float4 e0 = sE[tid + NM],            f0 = sF[tid + NM];
  const float4 e1 = sE[tid + THREADS + NM],  f1 = sF[tid + THREADS + NM];
  const bool  has3 = (tid < GHW - 2 * THREADS);   // tid < 50
  float4 e2 = make_float4(0,0,0,0), f2 = e2;
  if (has3) { e2 = sE[tid + 2*THREADS + NM]; f2 = sF[tid + 2*THREADS + NM]; }

  // Per-m accumulators for the 2 outputs (ii = tid, tid+256), 2 pols each.
  float A0r = 0.f, A0i = 0.f, A1r = 0.f, A1i = 0.f;   // out0 pol0/pol1
  float B0r = 0.f, B0i = 0.f, B1r = 0.f, B1i = 0.f;   // out1 pol0/pol1
  int kbase = 0, p = 0;

  for (int mm = -NM; mm <= NM; ++mm) {
    // ---- G/H phase into sGH[p] ----
    {
      const int s = NM - mm;
      {
        const float4 fm = sF[tid + s], em = sE[tid + s];
        sGH[p][tid] = make_float4(
          e0.x*fm.x + e0.y*fm.y + e0.z*fm.z + e0.w*fm.w,
          e0.y*fm.x - e0.x*fm.y + e0.w*fm.z - e0.z*fm.w,
          f0.x*em.x + f0.y*em.y + f0.z*em.z + f0.w*em.w,
          f0.y*em.x - f0.x*em.y + f0.w*em.z - f0.z*em.w);
      }
      {
        const float4 fm = sF[tid + THREADS + s], em = sE[tid + THREADS + s];
        sGH[p][tid + THREADS] = make_float4(
          e1.x*fm.x + e1.y*fm.y + e1.z*fm.z + e1.w*fm.w,
          e1.y*fm.x - e1.x*fm.y + e1.w*fm.z - e1.z*fm.w,
          f1.x*em.x + f1.y*em.y + f1.z*em.z + f1.w*em.w,
          f1.y*em.x - f1.x*em.y + f1.w*em.z - f1.z*em.w);
      }
      if (has3) {
        const float4 fm = sF[tid + 2*THREADS + s], em = sE[tid + 2*THREADS + s];
        sGH[p][tid + 2*THREADS] = make_float4(
          e2.x*fm.x + e2.y*fm.y + e2.z*fm.z + e2.w*fm.w,
          e2.y*fm.x - e2.x*fm.y + e2.w*fm.z - e2.z*fm.w,
          f2.x*em.x + f2.y*em.y + f2.z*em.z + f2.w*em.w,
          f2.y*em.x - f2.x*em.y + f2.w*em.z - f2.z*em.w);
      }
    }
    __syncthreads();   // single barrier per m (double buffer makes tail barrier redundant)

    // ---- FIR taps for this m ----
    const int am   = mm < 0 ? -mm : mm;
    const int nmax = (mm == 0) ? NM : (NM / am);
    const int T    = 2 * nmax + 1;
    float u1a=0.f,u2a=0.f,u3a=0.f,u4a=0.f, v1a=0.f,v2a=0.f,v3a=0.f,v4a=0.f;
    float u1b=0.f,u2b=0.f,u3b=0.f,u4b=0.f, v1b=0.f,v2b=0.f,v3b=0.f,v4b=0.f;
    const int a0 = tid + NM + nmax;            // out0 gh index at t=0
    const float4* __restrict__ gh = &sGH[p][0];
    #pragma unroll 2
    for (int t = 0; t < T; ++t) {
      const float4 c  = crow[kbase + t];       // uniform -> scalar load
      const float4 g0 = gh[a0 - t];            // out0
      const float4 g1 = gh[a0 - t + THREADS];  // out1: same addr + 4096B (offset imm)
      u1a += c.x*g0.x; u2a += c.y*g0.y; u3a += c.x*g0.y; u4a += c.y*g0.x;
      v1a += c.z*g0.z; v2a += c.w*g0.w; v3a += c.z*g0.w; v4a += c.w*g0.z;
      u1b += c.x*g1.x; u2b += c.y*g1.y; u3b += c.x*g1.y; u4b += c.y*g1.x;
      v1b += c.z*g1.z; v2b += c.w*g1.w; v3b += c.z*g1.w; v4b += c.w*g1.z;
    }
    kbase += T;
    const float sra = u1a - u2a + v1a - v2a, sia = u3a + u4a + v3a + v4a;
    const float srb = u1b - u2b + v1b - v2b, sib = u3b + u4b + v3b + v4b;
    const float4 ea = sE[tid + 2 * NM - mm];             // E[i - m], out0
    const float4 eb = sE[tid + THREADS + 2 * NM - mm];   // out1 (+4096B)
    A0r += sra * ea.x - sia * ea.y;  A0i += sra * ea.y + sia * ea.x;
    A1r += sra * ea.z - sia * ea.w;  A1i += sra * ea.w + sia * ea.z;
    B0r += srb * eb.x - sib * eb.y;  B0i += srb * eb.y + sib * eb.x;
    B1r += srb * eb.z - sib * eb.w;  B1i += srb * eb.w + sib * eb.z;
    p ^= 1;
  }

  // ---- Epilogue: write both outputs, (IMAG, REAL) element order ----
  const int end = lpad + nout;
  const size_t chunk1 = (size_t)BATCH * nout * 4;
  {
    const int i = i0 + tid;
    if (i < end) {
      const float4 ev = sE[tid + 2 * NM];
      const float4 fv = sF[tid + 2 * NM];
      const size_t o = ((size_t)b * nout + (size_t)(i - lpad)) * 4;
      ushort4 w0, w1;
      w0.x = f2bf(ev.y); w0.y = f2bf(ev.x); w0.z = f2bf(ev.w); w0.w = f2bf(ev.z);
      w1.x = f2bf(fv.y + pf * A0i); w1.y = f2bf(fv.x + pf * A0r);
      w1.z = f2bf(fv.w + pf * A1i); w1.w = f2bf(fv.z + pf * A1r);
      *reinterpret_cast<ushort4*>(out + o) = w0;
      *reinterpret_cast<ushort4*>(out + chunk1 + o) = w1;
    }
  }
  {
    const int i = i0 + tid + THREADS;
    if (i < end) {
      const float4 ev = sE[tid + THREADS + 2 * NM];
      const float4 fv = sF[tid + THREADS + 2 * NM];
      const size_t o = ((size_t)b * nout + (size_t)(i - lpad)) * 4;
      ushort4 w0, w1;
      w0.x = f2bf(ev.y); w0.y = f2bf(ev.x); w0.z = f2bf(ev.w); w0.w = f2bf(ev.z);
      w1.x = f2bf(fv.y + pf * B0i); w1.y = f2bf(fv.x + pf * B0r);
      w1.z = f2bf(fv.w + pf * B1i); w1.w = f2bf(fv.z + pf * B1r);
      *reinterpret_cast<ushort4*>(out + o) = w0;
      *reinterpret_cast<ushort4*>(out + chunk1 + o) = w1;
    }
  }
}

} // namespace

extern "C" void kernel_launch(void* const* d_in, const int* in_sizes, int n_in,
                              void* d_out, int out_size, void* d_ws, size_t ws_size,
                              hipStream_t stream) {
  const float* E_real  = (const float*)d_in[0];
  const float* E_imag  = (const float*)d_in[1];
  const float* F_real  = (const float*)d_in[2];
  const float* F_imag  = (const float*)d_in[3];
  const float* C1_real = (const float*)d_in[4];
  const float* C1_imag = (const float*)d_in[5];
  const float* C2_real = (const float*)d_in[6];
  const float* C2_imag = (const float*)d_in[7];
  const float* task    = (const float*)d_in[8];

  // out_size = per-output component count = 32 * nout.
  int nout = out_size / 32;
  if (nout < 1 || nout > NSEQ) nout = NSEQ - 100;
  const int lpad   = (NSEQ - nout) / 2;             // 50
  const int ntiles = (nout + TILE - 1) / TILE;      // 128

  unsigned short* outp = (unsigned short*)d_out;
  float4* cw = (float4*)d_ws;   // 28736 B scratch

  hipLaunchKernelGGL(prep_c_kernel, dim3((4 * KTAPS + 255) / 256), dim3(256), 0, stream,
                     C1_real, C1_imag, C2_real, C2_imag, cw);

  hipLaunchKernelGGL(hpbc_kernel, dim3(BATCH * ntiles), dim3(THREADS), 0, stream,
                     (const float2*)E_real, (const float2*)E_imag,
                     (const float2*)F_real, (const float2*)F_imag,
                     task, cw, outp, nout, lpad, ntiles);
}

// Round 22
// 97.152 us; speedup vs baseline: 1.4866x; 1.0805x over previous
//
#include <hip/hip_runtime.h>
#include <hip/hip_bf16.h>

// HPBC step — R=2 ADJACENT outputs + tap-load reuse + packed f32 FMA.
// Geometry (solved): dict inputs, true complex assembly; output chunks
// [E' | Eo], element storage (IMAG, REAL) per (b, i', pol); nout=65436, lpad=50.
// Eo = F + P^1.5 * Σ_m [FIR_n(c1·G_m + c2·H_m)]·E(i-m).

namespace {

constexpr int NSEQ    = 65536;
constexpr int BATCH   = 8;
constexpr int KTAPS   = 449;
constexpr int NM      = 25;
constexpr int THREADS = 256;
constexpr int TILE    = 512;                     // outputs per block (2/thread, adjacent)
constexpr int WIN     = TILE + 4 * NM;           // 612
constexpr int GHW     = TILE + 2 * NM;           // 562

typedef float v2f __attribute__((ext_vector_type(2)));

__device__ inline v2f pkfma(float s, v2f v, v2f acc) {
  return __builtin_elementwise_fma((v2f){s, s}, v, acc);
}

__device__ inline unsigned short f2bf(float f) {
  __hip_bfloat16 h = __float2bfloat16(f);
  union { __hip_bfloat16 hh; unsigned short u; } cv;
  cv.hh = h;
  return cv.u;
}

// cw[row*K + k] = (c1r, c1i, c2r, c2i)
__global__ void prep_c_kernel(const float* __restrict__ c1r, const float* __restrict__ c1i,
                              const float* __restrict__ c2r, const float* __restrict__ c2i,
                              float4* __restrict__ cw) {
  int idx = blockIdx.x * blockDim.x + threadIdx.x;
  if (idx < 4 * KTAPS) cw[idx] = make_float4(c1r[idx], c1i[idx], c2r[idx], c2i[idx]);
}

// (Gr,Gi) = Σ_p E[j,p]*conj(F[j-m,p]) packed as two pk chains; same for H.
__device__ inline float4 gh_entry(const float4 e, const float4 f,
                                  const float4 fm, const float4 em) {
  v2f G = (v2f){fm.w * e.w, fm.w * (-e.z)};
  G = pkfma(fm.x, (v2f){e.x, e.y}, G);
  G = pkfma(fm.y, (v2f){e.y, -e.x}, G);
  G = pkfma(fm.z, (v2f){e.z, e.w}, G);
  v2f H = (v2f){em.w * f.w, em.w * (-f.z)};
  H = pkfma(em.x, (v2f){f.x, f.y}, H);
  H = pkfma(em.y, (v2f){f.y, -f.x}, H);
  H = pkfma(em.z, (v2f){f.z, f.w}, H);
  return make_float4(G.x, G.y, H.x, H.y);
}

__global__ __launch_bounds__(THREADS, 4) void hpbc_kernel(
    const float2* __restrict__ er, const float2* __restrict__ ei,
    const float2* __restrict__ fr, const float2* __restrict__ fi,
    const float*  __restrict__ task, const float4* __restrict__ cw,
    unsigned short* __restrict__ out, int nout, int lpad, int ntiles)
{
  __shared__ float4 sE[WIN];      // (p0.re, p0.im, p1.re, p1.im)
  __shared__ float4 sF[WIN];
  __shared__ float4 sGH[2][GHW];  // double-buffered (Gr, Gi, Hr, Hi)

  const int bx   = blockIdx.x;
  const int b    = bx / ntiles;
  const int tile = bx - b * ntiles;
  const int tid  = threadIdx.x;
  const int i0   = lpad + tile * TILE;
  const int elo  = i0 - 2 * NM;

  const float2* erb = er + (size_t)b * NSEQ;
  const float2* eib = ei + (size_t)b * NSEQ;
  const float2* frb = fr + (size_t)b * NSEQ;
  const float2* fib = fi + (size_t)b * NSEQ;

  for (int u = tid; u < WIN; u += THREADS) {
    int g = (elo + u) & (NSEQ - 1);                  // exact jnp.roll wrap
    float2 a = erb[g], c = eib[g];
    sE[u] = make_float4(a.x, c.x, a.y, c.y);
    float2 d = frb[g], e = fib[g];
    sF[u] = make_float4(d.x, e.x, d.y, e.y);
  }

  const float dbm = task[b * 4 + 0];
  const float fsr = task[b * 4 + 2];
  const int   x   = (int)(fsr / 2.0e9f);
  const int ind = (x == 40) ? 1 : (x == 80) ? 2 : (x == 160) ? 3 : 0;
  const float4* __restrict__ crow = cw + ind * KTAPS;
  const float P  = powf(10.0f, dbm * 0.1f) * 0.5f;
  const float pf = P * sqrtf(P);

  __syncthreads();

  // Hoisted unshifted E[j], F[j] for this thread's gh entries.
  const float4 e0 = sE[tid + NM],            f0 = sF[tid + NM];
  const float4 e1 = sE[tid + THREADS + NM],  f1 = sF[tid + THREADS + NM];
  const bool  has3 = (tid < GHW - 2 * THREADS);   // tid < 50
  float4 e2 = make_float4(0,0,0,0), f2 = e2;
  if (has3) { e2 = sE[tid + 2*THREADS + NM]; f2 = sF[tid + 2*THREADS + NM]; }

  // m-level accumulators: outputs A (w=2tid), B (w=2tid+1), 2 pols each.
  v2f A0 = {0,0}, A1 = {0,0}, B0 = {0,0}, B1 = {0,0};   // (re, im)
  int kbase = 0, p = 0;

  for (int mm = -NM; mm <= NM; ++mm) {
    // ---- G/H phase into sGH[p] ----
    {
      const int s = NM - mm;
      sGH[p][tid]             = gh_entry(e0, f0, sF[tid + s],             sE[tid + s]);
      sGH[p][tid + THREADS]   = gh_entry(e1, f1, sF[tid + THREADS + s],   sE[tid + THREADS + s]);
      if (has3)
        sGH[p][tid + 2*THREADS] = gh_entry(e2, f2, sF[tid + 2*THREADS + s], sE[tid + 2*THREADS + s]);
    }
    __syncthreads();   // single barrier per m (double buffer)

    // ---- FIR taps: outputs A (w) and B (w+1) share loads (shift-by-1) ----
    const int am   = mm < 0 ? -mm : mm;
    const int nmax = (mm == 0) ? NM : (NM / am);
    const int T    = 2 * nmax + 1;
    const float4* __restrict__ gh = &sGH[p][0];
    const int base = 2 * tid + NM + nmax;     // A's gh index at t=0
    v2f aU13={0,0}, aU42={0,0}, aV13={0,0}, aV42={0,0};
    v2f bU13={0,0}, bU42={0,0}, bV13={0,0}, bV42={0,0};
    float4 cp;                                 // c[t-1] carried for A
    {
      const float4 g = gh[base + 1];
      cp = crow[kbase];
      const v2f glo = (v2f){g.x, g.y}, ghi = (v2f){g.z, g.w};
      bU13 = pkfma(cp.x, glo, bU13); bU42 = pkfma(cp.y, glo, bU42);
      bV13 = pkfma(cp.z, ghi, bV13); bV42 = pkfma(cp.w, ghi, bV42);
    }
    for (int t = 1; t < T; ++t) {
      const float4 g = gh[base + 1 - t];
      const float4 c = crow[kbase + t];
      const v2f glo = (v2f){g.x, g.y}, ghi = (v2f){g.z, g.w};
      bU13 = pkfma(c.x,  glo, bU13); bU42 = pkfma(c.y,  glo, bU42);
      bV13 = pkfma(c.z,  ghi, bV13); bV42 = pkfma(c.w,  ghi, bV42);
      aU13 = pkfma(cp.x, glo, aU13); aU42 = pkfma(cp.y, glo, aU42);
      aV13 = pkfma(cp.z, ghi, aV13); aV42 = pkfma(cp.w, ghi, aV42);
      cp = c;
    }
    {
      const float4 g = gh[base + 1 - T];      // A's tap T-1
      const v2f glo = (v2f){g.x, g.y}, ghi = (v2f){g.z, g.w};
      aU13 = pkfma(cp.x, glo, aU13); aU42 = pkfma(cp.y, glo, aU42);
      aV13 = pkfma(cp.z, ghi, aV13); aV42 = pkfma(cp.w, ghi, aV42);
    }
    kbase += T;

    // sr = u1-u2+v1-v2, si = u3+u4+v3+v4  (U13=(u1,u3), U42=(u4,u2), ...)
    const float sra = aU13.x - aU42.y + aV13.x - aV42.y;
    const float sia = aU13.y + aU42.x + aV13.y + aV42.x;
    const float srb = bU13.x - bU42.y + bV13.x - bV42.y;
    const float sib = bU13.y + bU42.x + bV13.y + bV42.x;

    // acc += T_m * E[i-m]  (complex; packed as (re,im))
    const float4 ea = sE[2*tid + 2*NM - mm];
    const float4 eb = sE[2*tid + 1 + 2*NM - mm];
    A0 = pkfma(sra, (v2f){ea.x, ea.y}, pkfma(sia, (v2f){-ea.y, ea.x}, A0));
    A1 = pkfma(sra, (v2f){ea.z, ea.w}, pkfma(sia, (v2f){-ea.w, ea.z}, A1));
    B0 = pkfma(srb, (v2f){eb.x, eb.y}, pkfma(sib, (v2f){-eb.y, eb.x}, B0));
    B1 = pkfma(srb, (v2f){eb.z, eb.w}, pkfma(sib, (v2f){-eb.w, eb.z}, B1));
    p ^= 1;
  }

  // ---- Epilogue: (IMAG, REAL) element order; adjacent outputs merge ----
  const int end = lpad + nout;
  const size_t chunk1 = (size_t)BATCH * nout * 4;
  const int i = i0 + 2 * tid;
  if (i + 1 < end) {
    const float4 evA = sE[2*tid + 2*NM],     fvA = sF[2*tid + 2*NM];
    const float4 evB = sE[2*tid + 1 + 2*NM], fvB = sF[2*tid + 1 + 2*NM];
    const size_t o = ((size_t)b * nout + (size_t)(i - lpad)) * 4;
    ushort4 w0a, w0b, w1a, w1b;
    w0a.x = f2bf(evA.y); w0a.y = f2bf(evA.x); w0a.z = f2bf(evA.w); w0a.w = f2bf(evA.z);
    w0b.x = f2bf(evB.y); w0b.y = f2bf(evB.x); w0b.z = f2bf(evB.w); w0b.w = f2bf(evB.z);
    w1a.x = f2bf(fvA.y + pf * A0.y); w1a.y = f2bf(fvA.x + pf * A0.x);
    w1a.z = f2bf(fvA.w + pf * A1.y); w1a.w = f2bf(fvA.z + pf * A1.x);
    w1b.x = f2bf(fvB.y + pf * B0.y); w1b.y = f2bf(fvB.x + pf * B0.x);
    w1b.z = f2bf(fvB.w + pf * B1.y); w1b.w = f2bf(fvB.z + pf * B1.x);
    *reinterpret_cast<ushort4*>(out + o) = w0a;
    *reinterpret_cast<ushort4*>(out + o + 4) = w0b;
    *reinterpret_cast<ushort4*>(out + chunk1 + o) = w1a;
    *reinterpret_cast<ushort4*>(out + chunk1 + o + 4) = w1b;
  } else if (i < end) {   // defensive odd tail (not hit for nout=65436)
    const float4 evA = sE[2*tid + 2*NM], fvA = sF[2*tid + 2*NM];
    const size_t o = ((size_t)b * nout + (size_t)(i - lpad)) * 4;
    ushort4 w0a, w1a;
    w0a.x = f2bf(evA.y); w0a.y = f2bf(evA.x); w0a.z = f2bf(evA.w); w0a.w = f2bf(evA.z);
    w1a.x = f2bf(fvA.y + pf * A0.y); w1a.y = f2bf(fvA.x + pf * A0.x);
    w1a.z = f2bf(fvA.w + pf * A1.y); w1a.w = f2bf(fvA.z + pf * A1.x);
    *reinterpret_cast<ushort4*>(out + o) = w0a;
    *reinterpret_cast<ushort4*>(out + chunk1 + o) = w1a;
  }
}

} // namespace

extern "C" void kernel_launch(void* const* d_in, const int* in_sizes, int n_in,
                              void* d_out, int out_size, void* d_ws, size_t ws_size,
                              hipStream_t stream) {
  const float* E_real  = (const float*)d_in[0];
  const float* E_imag  = (const float*)d_in[1];
  const float* F_real  = (const float*)d_in[2];
  const float* F_imag  = (const float*)d_in[3];
  const float* C1_real = (const float*)d_in[4];
  const float* C1_imag = (const float*)d_in[5];
  const float* C2_real = (const float*)d_in[6];
  const float* C2_imag = (const float*)d_in[7];
  const float* task    = (const float*)d_in[8];

  int nout = out_size / 32;
  if (nout < 1 || nout > NSEQ) nout = NSEQ - 100;
  const int lpad   = (NSEQ - nout) / 2;             // 50
  const int ntiles = (nout + TILE - 1) / TILE;      // 128

  unsigned short* outp = (unsigned short*)d_out;
  float4* cw = (float4*)d_ws;

  hipLaunchKernelGGL(prep_c_kernel, dim3((4 * KTAPS + 255) / 256), dim3(256), 0, stream,
                     C1_real, C1_imag, C2_real, C2_imag, cw);

  hipLaunchKernelGGL(hpbc_kernel, dim3(BATCH * ntiles), dim3(THREADS), 0, stream,
                     (const float2*)E_real, (const float2*)E_imag,
                     (const float2*)F_real, (const float2*)F_imag,
                     task, cw, outp, nout, lpad, ntiles);
}

// Round 23
// 96.330 us; speedup vs baseline: 1.4993x; 1.0085x over previous
//
#include <hip/hip_runtime.h>
#include <hip/hip_bf16.h>

// HPBC step — R=2 adjacent + tap sharing + pk-FMA + PARITY-SPLIT gh (bank-
// conflict-free FIR) + ea/eb carry.
// Geometry (solved): dict inputs, true complex assembly; output chunks
// [E' | Eo], element storage (IMAG, REAL) per (b, i', pol); nout=65436, lpad=50.

namespace {

constexpr int NSEQ    = 65536;
constexpr int BATCH   = 8;
constexpr int KTAPS   = 449;
constexpr int NM      = 25;
constexpr int THREADS = 256;
constexpr int TILE    = 512;                     // outputs per block (2/thread, adjacent)
constexpr int WIN     = TILE + 4 * NM;           // 612
constexpr int GHW     = TILE + 2 * NM;           // 562
constexpr int GHH     = (GHW + 1) / 2;           // 281 entries per parity array

typedef float v2f __attribute__((ext_vector_type(2)));

__device__ inline v2f pkfma(float s, v2f v, v2f acc) {
  return __builtin_elementwise_fma((v2f){s, s}, v, acc);
}

// 4 packed FMAs of one tap: c (c1r,c1i,c2r,c2i) × g (Gr,Gi,Hr,Hi).
__device__ inline void mac(v2f& U13, v2f& U42, v2f& V13, v2f& V42,
                           const float4 c, const float4 g) {
  const v2f glo = (v2f){g.x, g.y}, ghi = (v2f){g.z, g.w};
  U13 = pkfma(c.x, glo, U13); U42 = pkfma(c.y, glo, U42);
  V13 = pkfma(c.z, ghi, V13); V42 = pkfma(c.w, ghi, V42);
}

__device__ inline unsigned short f2bf(float f) {
  __hip_bfloat16 h = __float2bfloat16(f);
  union { __hip_bfloat16 hh; unsigned short u; } cv;
  cv.hh = h;
  return cv.u;
}

__global__ void prep_c_kernel(const float* __restrict__ c1r, const float* __restrict__ c1i,
                              const float* __restrict__ c2r, const float* __restrict__ c2i,
                              float4* __restrict__ cw) {
  int idx = blockIdx.x * blockDim.x + threadIdx.x;
  if (idx < 4 * KTAPS) cw[idx] = make_float4(c1r[idx], c1i[idx], c2r[idx], c2i[idx]);
}

// (Gr,Gi) = Σ_p E[j,p]*conj(F[j-m,p]); (Hr,Hi) with E<->F roles swapped.
__device__ inline float4 gh_entry(const float4 e, const float4 f,
                                  const float4 fm, const float4 em) {
  v2f G = (v2f){fm.w * e.w, fm.w * (-e.z)};
  G = pkfma(fm.x, (v2f){e.x, e.y}, G);
  G = pkfma(fm.y, (v2f){e.y, -e.x}, G);
  G = pkfma(fm.z, (v2f){e.z, e.w}, G);
  v2f H = (v2f){em.w * f.w, em.w * (-f.z)};
  H = pkfma(em.x, (v2f){f.x, f.y}, H);
  H = pkfma(em.y, (v2f){f.y, -f.x}, H);
  H = pkfma(em.z, (v2f){f.z, f.w}, H);
  return make_float4(G.x, G.y, H.x, H.y);
}

__global__ __launch_bounds__(THREADS, 4) void hpbc_kernel(
    const float2* __restrict__ er, const float2* __restrict__ ei,
    const float2* __restrict__ fr, const float2* __restrict__ fi,
    const float*  __restrict__ task, const float4* __restrict__ cw,
    unsigned short* __restrict__ out, int nout, int lpad, int ntiles)
{
  __shared__ float4 sE[WIN];
  __shared__ float4 sF[WIN];
  __shared__ float4 ghE[2][GHH];   // gh entries with even j, double-buffered
  __shared__ float4 ghO[2][GHH];   // odd j

  const int bx   = blockIdx.x;
  const int b    = bx / ntiles;
  const int tile = bx - b * ntiles;
  const int tid  = threadIdx.x;
  const int i0   = lpad + tile * TILE;
  const int elo  = i0 - 2 * NM;

  const float2* erb = er + (size_t)b * NSEQ;
  const float2* eib = ei + (size_t)b * NSEQ;
  const float2* frb = fr + (size_t)b * NSEQ;
  const float2* fib = fi + (size_t)b * NSEQ;

  for (int u = tid; u < WIN; u += THREADS) {
    int g = (elo + u) & (NSEQ - 1);                  // exact jnp.roll wrap
    float2 a = erb[g], c = eib[g];
    sE[u] = make_float4(a.x, c.x, a.y, c.y);
    float2 d = frb[g], e = fib[g];
    sF[u] = make_float4(d.x, e.x, d.y, e.y);
  }

  const float dbm = task[b * 4 + 0];
  const float fsr = task[b * 4 + 2];
  const int   x   = (int)(fsr / 2.0e9f);
  const int ind = (x == 40) ? 1 : (x == 80) ? 2 : (x == 160) ? 3 : 0;
  const float4* __restrict__ crow = cw + ind * KTAPS;
  const float P  = powf(10.0f, dbm * 0.1f) * 0.5f;
  const float pf = P * sqrtf(P);

  __syncthreads();

  const float4 e0 = sE[tid + NM],            f0 = sF[tid + NM];
  const float4 e1 = sE[tid + THREADS + NM],  f1 = sF[tid + THREADS + NM];
  const bool  has3 = (tid < GHW - 2 * THREADS);   // tid < 50
  float4 e2 = make_float4(0,0,0,0), f2 = e2;
  if (has3) { e2 = sE[tid + 2*THREADS + NM]; f2 = sF[tid + 2*THREADS + NM]; }

  v2f A0 = {0,0}, A1 = {0,0}, B0 = {0,0}, B1 = {0,0};   // (re, im) per pol
  int kbase = 0, p = 0;
  // eb(m) = ea(m-1); preload eb for the first iteration (mm = -NM):
  float4 ebCarry = sE[2*tid + 1 + 2*NM + NM];           // sE[2tid + 76]

  for (int mm = -NM; mm <= NM; ++mm) {
    // ---- G/H phase into parity-split buffers ----
    {
      const int s = NM - mm;
      const float4 g0 = gh_entry(e0, f0, sF[tid + s], sE[tid + s]);
      if (tid & 1) ghO[p][tid >> 1] = g0; else ghE[p][tid >> 1] = g0;
      const float4 g1 = gh_entry(e1, f1, sF[tid + THREADS + s], sE[tid + THREADS + s]);
      if (tid & 1) ghO[p][(tid + THREADS) >> 1] = g1; else ghE[p][(tid + THREADS) >> 1] = g1;
      if (has3) {
        const float4 g2 = gh_entry(e2, f2, sF[tid + 2*THREADS + s], sE[tid + 2*THREADS + s]);
        if (tid & 1) ghO[p][(tid + 2*THREADS) >> 1] = g2; else ghE[p][(tid + 2*THREADS) >> 1] = g2;
      }
    }
    __syncthreads();   // single barrier per m (double buffer)

    // ---- FIR: outputs A (w=2tid), B (w=2tid+1); pair-walk the parity arrays.
    // j = J0 - t, J0 = 2tid + NM + nmax + 1. hi_s = gh[J0-2s], lo_s = gh[J0-1-2s].
    // B: c[2s]*hi_s (s=0..n), c[2s+1]*lo_s (s=0..n-1)
    // A: c[2s]*lo_s (s=0..n), c[2s-1]*hi_s (s=1..n)
    const int am   = mm < 0 ? -mm : mm;
    const int nmax = (mm == 0) ? NM : (NM / am);
    const int q    = nmax & 1;                      // parity of J0 (lane-uniform)
    const float4* __restrict__ hiArr = q ? ghO[p] : ghE[p];
    const float4* __restrict__ loArr = q ? ghE[p] : ghO[p];
    const int h0 = tid + ((26 + nmax) >> 1);        // (J0)>>1 - base part
    const int h1 = tid + ((25 + nmax) >> 1);        // (J0-1)>>1

    v2f aU13={0,0}, aU42={0,0}, aV13={0,0}, aV42={0,0};
    v2f bU13={0,0}, bU42={0,0}, bV13={0,0}, bV42={0,0};
    float4 cOdd;                                    // c[2s+1] carried to s+1 for A
    {
      const float4 hi = hiArr[h0], lo = loArr[h1];
      const float4 c0 = crow[kbase], c1 = crow[kbase + 1];
      mac(bU13, bU42, bV13, bV42, c0, hi);
      mac(bU13, bU42, bV13, bV42, c1, lo);
      mac(aU13, aU42, aV13, aV42, c0, lo);
      cOdd = c1;
    }
    for (int s = 1; s < nmax; ++s) {
      const float4 hi = hiArr[h0 - s], lo = loArr[h1 - s];
      const float4 c2 = crow[kbase + 2*s], c3 = crow[kbase + 2*s + 1];
      mac(bU13, bU42, bV13, bV42, c2, hi);
      mac(bU13, bU42, bV13, bV42, c3, lo);
      mac(aU13, aU42, aV13, aV42, cOdd, hi);
      mac(aU13, aU42, aV13, aV42, c2, lo);
      cOdd = c3;
    }
    {
      const float4 hi = hiArr[h0 - nmax], lo = loArr[h1 - nmax];
      const float4 c2 = crow[kbase + 2*nmax];
      mac(bU13, bU42, bV13, bV42, c2, hi);
      mac(aU13, aU42, aV13, aV42, cOdd, hi);
      mac(aU13, aU42, aV13, aV42, c2, lo);
    }
    kbase += 2 * nmax + 1;

    const float sra = aU13.x - aU42.y + aV13.x - aV42.y;
    const float sia = aU13.y + aU42.x + aV13.y + aV42.x;
    const float srb = bU13.x - bU42.y + bV13.x - bV42.y;
    const float sib = bU13.y + bU42.x + bV13.y + bV42.x;

    const float4 ea = sE[2*tid + 2*NM - mm];        // E[i-m] for A
    const float4 eb = ebCarry;                      // = ea from previous m
    ebCarry = ea;
    A0 = pkfma(sra, (v2f){ea.x, ea.y}, pkfma(sia, (v2f){-ea.y, ea.x}, A0));
    A1 = pkfma(sra, (v2f){ea.z, ea.w}, pkfma(sia, (v2f){-ea.w, ea.z}, A1));
    B0 = pkfma(srb, (v2f){eb.x, eb.y}, pkfma(sib, (v2f){-eb.y, eb.x}, B0));
    B1 = pkfma(srb, (v2f){eb.z, eb.w}, pkfma(sib, (v2f){-eb.w, eb.z}, B1));
    p ^= 1;
  }

  // ---- Epilogue: (IMAG, REAL) element order ----
  const int end = lpad + nout;
  const size_t chunk1 = (size_t)BATCH * nout * 4;
  const int i = i0 + 2 * tid;
  if (i + 1 < end) {
    const float4 evA = sE[2*tid + 2*NM],     fvA = sF[2*tid + 2*NM];
    const float4 evB = sE[2*tid + 1 + 2*NM], fvB = sF[2*tid + 1 + 2*NM];
    const size_t o = ((size_t)b * nout + (size_t)(i - lpad)) * 4;
    ushort4 w0a, w0b, w1a, w1b;
    w0a.x = f2bf(evA.y); w0a.y = f2bf(evA.x); w0a.z = f2bf(evA.w); w0a.w = f2bf(evA.z);
    w0b.x = f2bf(evB.y); w0b.y = f2bf(evB.x); w0b.z = f2bf(evB.w); w0b.w = f2bf(evB.z);
    w1a.x = f2bf(fvA.y + pf * A0.y); w1a.y = f2bf(fvA.x + pf * A0.x);
    w1a.z = f2bf(fvA.w + pf * A1.y); w1a.w = f2bf(fvA.z + pf * A1.x);
    w1b.x = f2bf(fvB.y + pf * B0.y); w1b.y = f2bf(fvB.x + pf * B0.x);
    w1b.z = f2bf(fvB.w + pf * B1.y); w1b.w = f2bf(fvB.z + pf * B1.x);
    *reinterpret_cast<ushort4*>(out + o) = w0a;
    *reinterpret_cast<ushort4*>(out + o + 4) = w0b;
    *reinterpret_cast<ushort4*>(out + chunk1 + o) = w1a;
    *reinterpret_cast<ushort4*>(out + chunk1 + o + 4) = w1b;
  } else if (i < end) {   // defensive odd tail (not hit for nout=65436)
    const float4 evA = sE[2*tid + 2*NM], fvA = sF[2*tid + 2*NM];
    const size_t o = ((size_t)b * nout + (size_t)(i - lpad)) * 4;
    ushort4 w0a, w1a;
    w0a.x = f2bf(evA.y); w0a.y = f2bf(evA.x); w0a.z = f2bf(evA.w); w0a.w = f2bf(evA.z);
    w1a.x = f2bf(fvA.y + pf * A0.y); w1a.y = f2bf(fvA.x + pf * A0.x);
    w1a.z = f2bf(fvA.w + pf * A1.y); w1a.w = f2bf(fvA.z + pf * A1.x);
    *reinterpret_cast<ushort4*>(out + o) = w0a;
    *reinterpret_cast<ushort4*>(out + chunk1 + o) = w1a;
  }
}

} // namespace

extern "C" void kernel_launch(void* const* d_in, const int* in_sizes, int n_in,
                              void* d_out, int out_size, void* d_ws, size_t ws_size,
                              hipStream_t stream) {
  const float* E_real  = (const float*)d_in[0];
  const float* E_imag  = (const float*)d_in[1];
  const float* F_real  = (const float*)d_in[2];
  const float* F_imag  = (const float*)d_in[3];
  const float* C1_real = (const float*)d_in[4];
  const float* C1_imag = (const float*)d_in[5];
  const float* C2_real = (const float*)d_in[6];
  const float* C2_imag = (const float*)d_in[7];
  const float* task    = (const float*)d_in[8];

  int nout = out_size / 32;
  if (nout < 1 || nout > NSEQ) nout = NSEQ - 100;
  const int lpad   = (NSEQ - nout) / 2;             // 50
  const int ntiles = (nout + TILE - 1) / TILE;      // 128

  unsigned short* outp = (unsigned short*)d_out;
  float4* cw = (float4*)d_ws;

  hipLaunchKernelGGL(prep_c_kernel, dim3((4 * KTAPS + 255) / 256), dim3(256), 0, stream,
                     C1_real, C1_imag, C2_real, C2_imag, cw);

  hipLaunchKernelGGL(hpbc_kernel, dim3(BATCH * ntiles), dim3(THREADS), 0, stream,
                     (const float2*)E_real, (const float2*)E_imag,
                     (const float2*)F_real, (const float2*)F_imag,
                     task, cw, outp, nout, lpad, ntiles);
}

// Round 24
// 95.650 us; speedup vs baseline: 1.5100x; 1.0071x over previous
//
#include <hip/hip_runtime.h>
#include <hip/hip_bf16.h>

// HPBC step — R=2 adjacent + tap sharing + pk-FMA + parity-split gh +
// ROTATED LOOP: FIR(m) || GH(m+1) in one barrier-free region (overlaps the
// LDS-heavy FIR with the VALU-heavy GH phase; single barrier per m).
// Geometry (solved): dict inputs, true complex assembly; output chunks
// [E' | Eo], element storage (IMAG, REAL) per (b, i', pol); nout=65436, lpad=50.

namespace {

constexpr int NSEQ    = 65536;
constexpr int BATCH   = 8;
constexpr int KTAPS   = 449;
constexpr int NM      = 25;
constexpr int THREADS = 256;
constexpr int TILE    = 512;                     // outputs per block (2/thread, adjacent)
constexpr int WIN     = TILE + 4 * NM;           // 612
constexpr int GHW     = TILE + 2 * NM;           // 562
constexpr int GHH     = (GHW + 1) / 2;           // 281 entries per parity array

typedef float v2f __attribute__((ext_vector_type(2)));

__device__ inline v2f pkfma(float s, v2f v, v2f acc) {
  return __builtin_elementwise_fma((v2f){s, s}, v, acc);
}

__device__ inline void mac(v2f& U13, v2f& U42, v2f& V13, v2f& V42,
                           const float4 c, const float4 g) {
  const v2f glo = (v2f){g.x, g.y}, ghi = (v2f){g.z, g.w};
  U13 = pkfma(c.x, glo, U13); U42 = pkfma(c.y, glo, U42);
  V13 = pkfma(c.z, ghi, V13); V42 = pkfma(c.w, ghi, V42);
}

__device__ inline unsigned short f2bf(float f) {
  __hip_bfloat16 h = __float2bfloat16(f);
  union { __hip_bfloat16 hh; unsigned short u; } cv;
  cv.hh = h;
  return cv.u;
}

__global__ void prep_c_kernel(const float* __restrict__ c1r, const float* __restrict__ c1i,
                              const float* __restrict__ c2r, const float* __restrict__ c2i,
                              float4* __restrict__ cw) {
  int idx = blockIdx.x * blockDim.x + threadIdx.x;
  if (idx < 4 * KTAPS) cw[idx] = make_float4(c1r[idx], c1i[idx], c2r[idx], c2i[idx]);
}

// (Gr,Gi) = Σ_p E[j,p]*conj(F[j-m,p]); (Hr,Hi) with E<->F roles swapped.
__device__ inline float4 gh_entry(const float4 e, const float4 f,
                                  const float4 fm, const float4 em) {
  v2f G = (v2f){fm.w * e.w, fm.w * (-e.z)};
  G = pkfma(fm.x, (v2f){e.x, e.y}, G);
  G = pkfma(fm.y, (v2f){e.y, -e.x}, G);
  G = pkfma(fm.z, (v2f){e.z, e.w}, G);
  v2f H = (v2f){em.w * f.w, em.w * (-f.z)};
  H = pkfma(em.x, (v2f){f.x, f.y}, H);
  H = pkfma(em.y, (v2f){f.y, -f.x}, H);
  H = pkfma(em.z, (v2f){f.z, f.w}, H);
  return make_float4(G.x, G.y, H.x, H.y);
}

__global__ __launch_bounds__(THREADS, 4) void hpbc_kernel(
    const float2* __restrict__ er, const float2* __restrict__ ei,
    const float2* __restrict__ fr, const float2* __restrict__ fi,
    const float*  __restrict__ task, const float4* __restrict__ cw,
    unsigned short* __restrict__ out, int nout, int lpad, int ntiles)
{
  __shared__ float4 sE[WIN];
  __shared__ float4 sF[WIN];
  __shared__ float4 ghE[2][GHH];   // gh entries with even j, double-buffered
  __shared__ float4 ghO[2][GHH];   // odd j

  const int bx   = blockIdx.x;
  const int b    = bx / ntiles;
  const int tile = bx - b * ntiles;
  const int tid  = threadIdx.x;
  const int i0   = lpad + tile * TILE;
  const int elo  = i0 - 2 * NM;

  const float2* erb = er + (size_t)b * NSEQ;
  const float2* eib = ei + (size_t)b * NSEQ;
  const float2* frb = fr + (size_t)b * NSEQ;
  const float2* fib = fi + (size_t)b * NSEQ;

  for (int u = tid; u < WIN; u += THREADS) {
    int g = (elo + u) & (NSEQ - 1);                  // exact jnp.roll wrap
    float2 a = erb[g], c = eib[g];
    sE[u] = make_float4(a.x, c.x, a.y, c.y);
    float2 d = frb[g], e = fib[g];
    sF[u] = make_float4(d.x, e.x, d.y, e.y);
  }

  const float dbm = task[b * 4 + 0];
  const float fsr = task[b * 4 + 2];
  const int   x   = (int)(fsr / 2.0e9f);
  const int ind = (x == 40) ? 1 : (x == 80) ? 2 : (x == 160) ? 3 : 0;
  const float4* __restrict__ crow = cw + ind * KTAPS;
  const float P  = powf(10.0f, dbm * 0.1f) * 0.5f;
  const float pf = P * sqrtf(P);

  __syncthreads();   // sE/sF ready

  const float4 e0 = sE[tid + NM],            f0 = sF[tid + NM];
  const float4 e1 = sE[tid + THREADS + NM],  f1 = sF[tid + THREADS + NM];
  const bool  has3 = (tid < GHW - 2 * THREADS);   // tid < 50
  float4 e2 = make_float4(0,0,0,0), f2 = e2;
  if (has3) { e2 = sE[tid + 2*THREADS + NM]; f2 = sF[tid + 2*THREADS + NM]; }

  auto write_gh = [&](int pp, int mmNext) {
    const int s = NM - mmNext;
    const float4 g0 = gh_entry(e0, f0, sF[tid + s], sE[tid + s]);
    if (tid & 1) ghO[pp][tid >> 1] = g0; else ghE[pp][tid >> 1] = g0;
    const float4 g1 = gh_entry(e1, f1, sF[tid + THREADS + s], sE[tid + THREADS + s]);
    if (tid & 1) ghO[pp][(tid + THREADS) >> 1] = g1; else ghE[pp][(tid + THREADS) >> 1] = g1;
    if (has3) {
      const float4 g2 = gh_entry(e2, f2, sF[tid + 2*THREADS + s], sE[tid + 2*THREADS + s]);
      if (tid & 1) ghO[pp][(tid + 2*THREADS) >> 1] = g2; else ghE[pp][(tid + 2*THREADS) >> 1] = g2;
    }
  };

  v2f A0 = {0,0}, A1 = {0,0}, B0 = {0,0}, B1 = {0,0};   // (re, im) per pol
  int kbase = 0, p = 0;
  float4 ebCarry = sE[2*tid + 1 + 2*NM + NM];           // eb for first m

  // Prologue: GH for mm = -NM into buffer 0.
  write_gh(0, -NM);
  __syncthreads();

  for (int mm = -NM; mm <= NM; ++mm) {
    // ---- FIR(mm) from buf p (LDS-heavy) — overlapped with GH(mm+1) below ----
    const int am   = mm < 0 ? -mm : mm;
    const int nmax = (mm == 0) ? NM : (NM / am);
    const int q    = nmax & 1;
    const float4* __restrict__ hiArr = q ? ghO[p] : ghE[p];
    const float4* __restrict__ loArr = q ? ghE[p] : ghO[p];
    const int h0 = tid + ((26 + nmax) >> 1);
    const int h1 = tid + ((25 + nmax) >> 1);

    v2f aU13={0,0}, aU42={0,0}, aV13={0,0}, aV42={0,0};
    v2f bU13={0,0}, bU42={0,0}, bV13={0,0}, bV42={0,0};
    float4 cOdd;
    {
      const float4 hi = hiArr[h0], lo = loArr[h1];
      const float4 c0 = crow[kbase], c1 = crow[kbase + 1];
      mac(bU13, bU42, bV13, bV42, c0, hi);
      mac(bU13, bU42, bV13, bV42, c1, lo);
      mac(aU13, aU42, aV13, aV42, c0, lo);
      cOdd = c1;
    }
    for (int s = 1; s < nmax; ++s) {
      const float4 hi = hiArr[h0 - s], lo = loArr[h1 - s];
      const float4 c2 = crow[kbase + 2*s], c3 = crow[kbase + 2*s + 1];
      mac(bU13, bU42, bV13, bV42, c2, hi);
      mac(bU13, bU42, bV13, bV42, c3, lo);
      mac(aU13, aU42, aV13, aV42, cOdd, hi);
      mac(aU13, aU42, aV13, aV42, c2, lo);
      cOdd = c3;
    }
    {
      const float4 hi = hiArr[h0 - nmax], lo = loArr[h1 - nmax];
      const float4 c2 = crow[kbase + 2*nmax];
      mac(bU13, bU42, bV13, bV42, c2, hi);
      mac(aU13, aU42, aV13, aV42, cOdd, hi);
      mac(aU13, aU42, aV13, aV42, c2, lo);
    }
    kbase += 2 * nmax + 1;

    // ---- GH(mm+1) into buf p^1 (VALU-heavy; independent of FIR above) ----
    if (mm < NM) write_gh(p ^ 1, mm + 1);

    // ---- Reduce + accumulate this m ----
    const float sra = aU13.x - aU42.y + aV13.x - aV42.y;
    const float sia = aU13.y + aU42.x + aV13.y + aV42.x;
    const float srb = bU13.x - bU42.y + bV13.x - bV42.y;
    const float sib = bU13.y + bU42.x + bV13.y + bV42.x;

    const float4 ea = sE[2*tid + 2*NM - mm];
    const float4 eb = ebCarry;
    ebCarry = ea;
    A0 = pkfma(sra, (v2f){ea.x, ea.y}, pkfma(sia, (v2f){-ea.y, ea.x}, A0));
    A1 = pkfma(sra, (v2f){ea.z, ea.w}, pkfma(sia, (v2f){-ea.w, ea.z}, A1));
    B0 = pkfma(srb, (v2f){eb.x, eb.y}, pkfma(sib, (v2f){-eb.y, eb.x}, B0));
    B1 = pkfma(srb, (v2f){eb.z, eb.w}, pkfma(sib, (v2f){-eb.w, eb.z}, B1));

    __syncthreads();   // buf p^1 complete; everyone done reading buf p
    p ^= 1;
  }

  // ---- Epilogue: (IMAG, REAL) element order ----
  const int end = lpad + nout;
  const size_t chunk1 = (size_t)BATCH * nout * 4;
  const int i = i0 + 2 * tid;
  if (i + 1 < end) {
    const float4 evA = sE[2*tid + 2*NM],     fvA = sF[2*tid + 2*NM];
    const float4 evB = sE[2*tid + 1 + 2*NM], fvB = sF[2*tid + 1 + 2*NM];
    const size_t o = ((size_t)b * nout + (size_t)(i - lpad)) * 4;
    ushort4 w0a, w0b, w1a, w1b;
    w0a.x = f2bf(evA.y); w0a.y = f2bf(evA.x); w0a.z = f2bf(evA.w); w0a.w = f2bf(evA.z);
    w0b.x = f2bf(evB.y); w0b.y = f2bf(evB.x); w0b.z = f2bf(evB.w); w0b.w = f2bf(evB.z);
    w1a.x = f2bf(fvA.y + pf * A0.y); w1a.y = f2bf(fvA.x + pf * A0.x);
    w1a.z = f2bf(fvA.w + pf * A1.y); w1a.w = f2bf(fvA.z + pf * A1.x);
    w1b.x = f2bf(fvB.y + pf * B0.y); w1b.y = f2bf(fvB.x + pf * B0.x);
    w1b.z = f2bf(fvB.w + pf * B1.y); w1b.w = f2bf(fvB.z + pf * B1.x);
    *reinterpret_cast<ushort4*>(out + o) = w0a;
    *reinterpret_cast<ushort4*>(out + o + 4) = w0b;
    *reinterpret_cast<ushort4*>(out + chunk1 + o) = w1a;
    *reinterpret_cast<ushort4*>(out + chunk1 + o + 4) = w1b;
  } else if (i < end) {   // defensive odd tail (not hit for nout=65436)
    const float4 evA = sE[2*tid + 2*NM], fvA = sF[2*tid + 2*NM];
    const size_t o = ((size_t)b * nout + (size_t)(i - lpad)) * 4;
    ushort4 w0a, w1a;
    w0a.x = f2bf(evA.y); w0a.y = f2bf(evA.x); w0a.z = f2bf(evA.w); w0a.w = f2bf(evA.z);
    w1a.x = f2bf(fvA.y + pf * A0.y); w1a.y = f2bf(fvA.x + pf * A0.x);
    w1a.z = f2bf(fvA.w + pf * A1.y); w1a.w = f2bf(fvA.z + pf * A1.x);
    *reinterpret_cast<ushort4*>(out + o) = w0a;
    *reinterpret_cast<ushort4*>(out + chunk1 + o) = w1a;
  }
}

} // namespace

extern "C" void kernel_launch(void* const* d_in, const int* in_sizes, int n_in,
                              void* d_out, int out_size, void* d_ws, size_t ws_size,
                              hipStream_t stream) {
  const float* E_real  = (const float*)d_in[0];
  const float* E_imag  = (const float*)d_in[1];
  const float* F_real  = (const float*)d_in[2];
  const float* F_imag  = (const float*)d_in[3];
  const float* C1_real = (const float*)d_in[4];
  const float* C1_imag = (const float*)d_in[5];
  const float* C2_real = (const float*)d_in[6];
  const float* C2_imag = (const float*)d_in[7];
  const float* task    = (const float*)d_in[8];

  int nout = out_size / 32;
  if (nout < 1 || nout > NSEQ) nout = NSEQ - 100;
  const int lpad   = (NSEQ - nout) / 2;             // 50
  const int ntiles = (nout + TILE - 1) / TILE;      // 128

  unsigned short* outp = (unsigned short*)d_out;
  float4* cw = (float4*)d_ws;

  hipLaunchKernelGGL(prep_c_kernel, dim3((4 * KTAPS + 255) / 256), dim3(256), 0, stream,
                     C1_real, C1_imag, C2_real, C2_imag, cw);

  hipLaunchKernelGGL(hpbc_kernel, dim3(BATCH * ntiles), dim3(THREADS), 0, stream,
                     (const float2*)E_real, (const float2*)E_imag,
                     (const float2*)F_real, (const float2*)F_imag,
                     task, cw, outp, nout, lpad, ntiles);
}

// Round 25
// 88.319 us; speedup vs baseline: 1.6353x; 1.0830x over previous
//
#include <hip/hip_runtime.h>
#include <hip/hip_bf16.h>

// HPBC step — compile-time-specialized FIR (template<NMAX>, full unroll) +
// statically-named double buffers (alias-provable) + R=2 tap sharing + pk-FMA.
// Geometry (solved): dict inputs, true complex assembly; output chunks
// [E' | Eo], element storage (IMAG, REAL) per (b, i', pol); nout=65436, lpad=50.

namespace {

constexpr int NSEQ    = 65536;
constexpr int BATCH   = 8;
constexpr int KTAPS   = 449;
constexpr int NM      = 25;
constexpr int THREADS = 256;
constexpr int TILE    = 512;
constexpr int WIN     = TILE + 4 * NM;           // 612
constexpr int GHW     = TILE + 2 * NM;           // 562
constexpr int GHH     = (GHW + 1) / 2;           // 281 per parity array

typedef float v2f __attribute__((ext_vector_type(2)));

__device__ inline v2f pkfma(float s, v2f v, v2f acc) {
  return __builtin_elementwise_fma((v2f){s, s}, v, acc);
}

__device__ inline void mac(v2f& U13, v2f& U42, v2f& V13, v2f& V42,
                           const float4 c, const float4 g) {
  const v2f glo = (v2f){g.x, g.y}, ghi = (v2f){g.z, g.w};
  U13 = pkfma(c.x, glo, U13); U42 = pkfma(c.y, glo, U42);
  V13 = pkfma(c.z, ghi, V13); V42 = pkfma(c.w, ghi, V42);
}

__device__ inline unsigned short f2bf(float f) {
  __hip_bfloat16 h = __float2bfloat16(f);
  union { __hip_bfloat16 hh; unsigned short u; } cv;
  cv.hh = h;
  return cv.u;
}

__global__ void prep_c_kernel(const float* __restrict__ c1r, const float* __restrict__ c1i,
                              const float* __restrict__ c2r, const float* __restrict__ c2i,
                              float4* __restrict__ cw) {
  int idx = blockIdx.x * blockDim.x + threadIdx.x;
  if (idx < 4 * KTAPS) cw[idx] = make_float4(c1r[idx], c1i[idx], c2r[idx], c2i[idx]);
}

__device__ inline float4 gh_entry(const float4 e, const float4 f,
                                  const float4 fm, const float4 em) {
  v2f G = (v2f){fm.w * e.w, fm.w * (-e.z)};
  G = pkfma(fm.x, (v2f){e.x, e.y}, G);
  G = pkfma(fm.y, (v2f){e.y, -e.x}, G);
  G = pkfma(fm.z, (v2f){e.z, e.w}, G);
  v2f H = (v2f){em.w * f.w, em.w * (-f.z)};
  H = pkfma(em.x, (v2f){f.x, f.y}, H);
  H = pkfma(em.y, (v2f){f.y, -f.x}, H);
  H = pkfma(em.z, (v2f){f.z, f.w}, H);
  return make_float4(G.x, G.y, H.x, H.y);
}

// Fully-unrolled FIR for one m with tap count T = 2*NMAX+1.
// Outputs A (w=2tid) and B (w=2tid+1) share gh loads (shift-by-1 walk).
template<int NMAX>
__device__ inline void fir_unrolled(const float4* __restrict__ hiArr,
                                    const float4* __restrict__ loArr,
                                    const float4* __restrict__ cc,
                                    int tid,
                                    v2f& aU13, v2f& aU42, v2f& aV13, v2f& aV42,
                                    v2f& bU13, v2f& bU42, v2f& bV13, v2f& bV42)
{
  const int h0 = tid + ((26 + NMAX) >> 1);
  const int h1 = tid + ((25 + NMAX) >> 1);
  float4 cOdd;
  {
    const float4 hi = hiArr[h0], lo = loArr[h1];
    const float4 c0 = cc[0], c1 = cc[1];
    mac(bU13, bU42, bV13, bV42, c0, hi);
    mac(bU13, bU42, bV13, bV42, c1, lo);
    mac(aU13, aU42, aV13, aV42, c0, lo);
    cOdd = c1;
  }
#pragma unroll
  for (int s = 1; s < NMAX; ++s) {
    const float4 hi = hiArr[h0 - s], lo = loArr[h1 - s];
    const float4 c2 = cc[2*s], c3 = cc[2*s + 1];
    mac(bU13, bU42, bV13, bV42, c2, hi);
    mac(bU13, bU42, bV13, bV42, c3, lo);
    mac(aU13, aU42, aV13, aV42, cOdd, hi);
    mac(aU13, aU42, aV13, aV42, c2, lo);
    cOdd = c3;
  }
  {
    const float4 hi = hiArr[h0 - NMAX], lo = loArr[h1 - NMAX];
    const float4 c2 = cc[2*NMAX];
    mac(bU13, bU42, bV13, bV42, c2, hi);
    mac(aU13, aU42, aV13, aV42, cOdd, hi);
    mac(aU13, aU42, aV13, aV42, c2, lo);
  }
}

__global__ __launch_bounds__(THREADS, 4) void hpbc_kernel(
    const float2* __restrict__ er, const float2* __restrict__ ei,
    const float2* __restrict__ fr, const float2* __restrict__ fi,
    const float*  __restrict__ task, const float4* __restrict__ cw,
    unsigned short* __restrict__ out, int nout, int lpad, int ntiles)
{
  __shared__ float4 sE[WIN];
  __shared__ float4 sF[WIN];
  __shared__ float4 ghE0[GHH], ghO0[GHH];   // statically-named double buffers
  __shared__ float4 ghE1[GHH], ghO1[GHH];

  const int bx   = blockIdx.x;
  const int b    = bx / ntiles;
  const int tile = bx - b * ntiles;
  const int tid  = threadIdx.x;
  const int i0   = lpad + tile * TILE;
  const int elo  = i0 - 2 * NM;

  const float2* erb = er + (size_t)b * NSEQ;
  const float2* eib = ei + (size_t)b * NSEQ;
  const float2* frb = fr + (size_t)b * NSEQ;
  const float2* fib = fi + (size_t)b * NSEQ;

  for (int u = tid; u < WIN; u += THREADS) {
    int g = (elo + u) & (NSEQ - 1);                  // exact jnp.roll wrap
    float2 a = erb[g], c = eib[g];
    sE[u] = make_float4(a.x, c.x, a.y, c.y);
    float2 d = frb[g], e = fib[g];
    sF[u] = make_float4(d.x, e.x, d.y, e.y);
  }

  const float dbm = task[b * 4 + 0];
  const float fsr = task[b * 4 + 2];
  const int   x   = (int)(fsr / 2.0e9f);
  const int ind = (x == 40) ? 1 : (x == 80) ? 2 : (x == 160) ? 3 : 0;
  const float4* __restrict__ crow = cw + ind * KTAPS;
  const float P  = powf(10.0f, dbm * 0.1f) * 0.5f;
  const float pf = P * sqrtf(P);

  __syncthreads();

  const float4 e0 = sE[tid + NM],            f0 = sF[tid + NM];
  const float4 e1 = sE[tid + THREADS + NM],  f1 = sF[tid + THREADS + NM];
  const bool  has3 = (tid < GHW - 2 * THREADS);   // tid < 50
  float4 e2 = make_float4(0,0,0,0), f2 = e2;
  if (has3) { e2 = sE[tid + 2*THREADS + NM]; f2 = sF[tid + 2*THREADS + NM]; }

  v2f A0 = {0,0}, A1 = {0,0}, B0 = {0,0}, B1 = {0,0};
  int kbase = 0;
  float4 ebCarry = sE[2*tid + 1 + 2*NM + NM];

  auto write_gh = [&](float4* wE, float4* wO, int mmNext) {
    const int s = NM - mmNext;
    const float4 g0 = gh_entry(e0, f0, sF[tid + s], sE[tid + s]);
    if (tid & 1) wO[tid >> 1] = g0; else wE[tid >> 1] = g0;
    const float4 g1 = gh_entry(e1, f1, sF[tid + THREADS + s], sE[tid + THREADS + s]);
    if (tid & 1) wO[(tid + THREADS) >> 1] = g1; else wE[(tid + THREADS) >> 1] = g1;
    if (has3) {
      const float4 g2 = gh_entry(e2, f2, sF[tid + 2*THREADS + s], sE[tid + 2*THREADS + s]);
      if (tid & 1) wO[(tid + 2*THREADS) >> 1] = g2; else wE[(tid + 2*THREADS) >> 1] = g2;
    }
  };

  auto iter = [&](const float4* rE, const float4* rO,
                  float4* wE, float4* wO, int mm) {
    const int am   = mm < 0 ? -mm : mm;
    const int nmax = (mm == 0) ? NM : (NM / am);
    const int q    = nmax & 1;
    const float4* hiArr = q ? rO : rE;
    const float4* loArr = q ? rE : rO;
    const float4* cc = crow + kbase;

    v2f aU13={0,0}, aU42={0,0}, aV13={0,0}, aV42={0,0};
    v2f bU13={0,0}, bU42={0,0}, bV13={0,0}, bV42={0,0};
    switch (nmax) {
      case 25: fir_unrolled<25>(hiArr, loArr, cc, tid, aU13,aU42,aV13,aV42, bU13,bU42,bV13,bV42); break;
      case 12: fir_unrolled<12>(hiArr, loArr, cc, tid, aU13,aU42,aV13,aV42, bU13,bU42,bV13,bV42); break;
      case  8: fir_unrolled< 8>(hiArr, loArr, cc, tid, aU13,aU42,aV13,aV42, bU13,bU42,bV13,bV42); break;
      case  6: fir_unrolled< 6>(hiArr, loArr, cc, tid, aU13,aU42,aV13,aV42, bU13,bU42,bV13,bV42); break;
      case  5: fir_unrolled< 5>(hiArr, loArr, cc, tid, aU13,aU42,aV13,aV42, bU13,bU42,bV13,bV42); break;
      case  4: fir_unrolled< 4>(hiArr, loArr, cc, tid, aU13,aU42,aV13,aV42, bU13,bU42,bV13,bV42); break;
      case  3: fir_unrolled< 3>(hiArr, loArr, cc, tid, aU13,aU42,aV13,aV42, bU13,bU42,bV13,bV42); break;
      case  2: fir_unrolled< 2>(hiArr, loArr, cc, tid, aU13,aU42,aV13,aV42, bU13,bU42,bV13,bV42); break;
      default: fir_unrolled< 1>(hiArr, loArr, cc, tid, aU13,aU42,aV13,aV42, bU13,bU42,bV13,bV42); break;
    }
    kbase += 2 * nmax + 1;

    if (mm < NM) write_gh(wE, wO, mm + 1);

    const float sra = aU13.x - aU42.y + aV13.x - aV42.y;
    const float sia = aU13.y + aU42.x + aV13.y + aV42.x;
    const float srb = bU13.x - bU42.y + bV13.x - bV42.y;
    const float sib = bU13.y + bU42.x + bV13.y + bV42.x;

    const float4 ea = sE[2*tid + 2*NM - mm];
    const float4 eb = ebCarry;
    ebCarry = ea;
    A0 = pkfma(sra, (v2f){ea.x, ea.y}, pkfma(sia, (v2f){-ea.y, ea.x}, A0));
    A1 = pkfma(sra, (v2f){ea.z, ea.w}, pkfma(sia, (v2f){-ea.w, ea.z}, A1));
    B0 = pkfma(srb, (v2f){eb.x, eb.y}, pkfma(sib, (v2f){-eb.y, eb.x}, B0));
    B1 = pkfma(srb, (v2f){eb.z, eb.w}, pkfma(sib, (v2f){-eb.w, eb.z}, B1));

    __syncthreads();
  };

  // Prologue: GH(-NM) into buffer 0.
  write_gh(ghE0, ghO0, -NM);
  __syncthreads();

  for (int mm = -NM; mm <= NM; mm += 2) {
    iter(ghE0, ghO0, ghE1, ghO1, mm);          // reads buf0, writes buf1
    if (mm + 1 <= NM)
      iter(ghE1, ghO1, ghE0, ghO0, mm + 1);    // reads buf1, writes buf0
  }

  // ---- Epilogue: (IMAG, REAL) element order ----
  const int end = lpad + nout;
  const size_t chunk1 = (size_t)BATCH * nout * 4;
  const int i = i0 + 2 * tid;
  if (i + 1 < end) {
    const float4 evA = sE[2*tid + 2*NM],     fvA = sF[2*tid + 2*NM];
    const float4 evB = sE[2*tid + 1 + 2*NM], fvB = sF[2*tid + 1 + 2*NM];
    const size_t o = ((size_t)b * nout + (size_t)(i - lpad)) * 4;
    ushort4 w0a, w0b, w1a, w1b;
    w0a.x = f2bf(evA.y); w0a.y = f2bf(evA.x); w0a.z = f2bf(evA.w); w0a.w = f2bf(evA.z);
    w0b.x = f2bf(evB.y); w0b.y = f2bf(evB.x); w0b.z = f2bf(evB.w); w0b.w = f2bf(evB.z);
    w1a.x = f2bf(fvA.y + pf * A0.y); w1a.y = f2bf(fvA.x + pf * A0.x);
    w1a.z = f2bf(fvA.w + pf * A1.y); w1a.w = f2bf(fvA.z + pf * A1.x);
    w1b.x = f2bf(fvB.y + pf * B0.y); w1b.y = f2bf(fvB.x + pf * B0.x);
    w1b.z = f2bf(fvB.w + pf * B1.y); w1b.w = f2bf(fvB.z + pf * B1.x);
    *reinterpret_cast<ushort4*>(out + o) = w0a;
    *reinterpret_cast<ushort4*>(out + o + 4) = w0b;
    *reinterpret_cast<ushort4*>(out + chunk1 + o) = w1a;
    *reinterpret_cast<ushort4*>(out + chunk1 + o + 4) = w1b;
  } else if (i < end) {
    const float4 evA = sE[2*tid + 2*NM], fvA = sF[2*tid + 2*NM];
    const size_t o = ((size_t)b * nout + (size_t)(i - lpad)) * 4;
    ushort4 w0a, w1a;
    w0a.x = f2bf(evA.y); w0a.y = f2bf(evA.x); w0a.z = f2bf(evA.w); w0a.w = f2bf(evA.z);
    w1a.x = f2bf(fvA.y + pf * A0.y); w1a.y = f2bf(fvA.x + pf * A0.x);
    w1a.z = f2bf(fvA.w + pf * A1.y); w1a.w = f2bf(fvA.z + pf * A1.x);
    *reinterpret_cast<ushort4*>(out + o) = w0a;
    *reinterpret_cast<ushort4*>(out + chunk1 + o) = w1a;
  }
}

} // namespace

extern "C" void kernel_launch(void* const* d_in, const int* in_sizes, int n_in,
                              void* d_out, int out_size, void* d_ws, size_t ws_size,
                              hipStream_t stream) {
  const float* E_real  = (const float*)d_in[0];
  const float* E_imag  = (const float*)d_in[1];
  const float* F_real  = (const float*)d_in[2];
  const float* F_imag  = (const float*)d_in[3];
  const float* C1_real = (const float*)d_in[4];
  const float* C1_imag = (const float*)d_in[5];
  const float* C2_real = (const float*)d_in[6];
  const float* C2_imag = (const float*)d_in[7];
  const float* task    = (const float*)d_in[8];

  int nout = out_size / 32;
  if (nout < 1 || nout > NSEQ) nout = NSEQ - 100;
  const int lpad   = (NSEQ - nout) / 2;             // 50
  const int ntiles = (nout + TILE - 1) / TILE;      // 128

  unsigned short* outp = (unsigned short*)d_out;
  float4* cw = (float4*)d_ws;

  hipLaunchKernelGGL(prep_c_kernel, dim3((4 * KTAPS + 255) / 256), dim3(256), 0, stream,
                     C1_real, C1_imag, C2_real, C2_imag, cw);

  hipLaunchKernelGGL(hpbc_kernel, dim3(BATCH * ntiles), dim3(THREADS), 0, stream,
                     (const float2*)E_real, (const float2*)E_imag,
                     (const float2*)F_real, (const float2*)F_imag,
                     task, cw, outp, nout, lpad, ntiles);
}

// Round 26
// 80.044 us; speedup vs baseline: 1.8044x; 1.1034x over previous
//
#include <hip/hip_runtime.h>
#include <hip/hip_bf16.h>

// HPBC step — ±m shared G/H (G_{-m}[j]=conj(H_m[j+m])) + template FIR +
// static double buffers + R=2 tap sharing + pk-FMA + parity-split gh.
// Geometry (solved): dict inputs, true complex assembly; output chunks
// [E' | Eo], element storage (IMAG, REAL) per (b, i', pol); nout=65436, lpad=50.

namespace {

constexpr int NSEQ    = 65536;
constexpr int BATCH   = 8;
constexpr int KTAPS   = 449;
constexpr int NM      = 25;
constexpr int THREADS = 256;
constexpr int TILE    = 512;
constexpr int WIN     = TILE + 4 * NM;           // 612
constexpr int GHW     = TILE + 2 * NM + 1;       // 563: bi = j+25, j in [-25, 537]
constexpr int GHH     = 282;                     // per parity array

typedef float v2f __attribute__((ext_vector_type(2)));

__device__ inline v2f pkfma(float s, v2f v, v2f acc) {
  return __builtin_elementwise_fma((v2f){s, s}, v, acc);
}

__device__ inline void mac(v2f& U13, v2f& U42, v2f& V13, v2f& V42,
                           const float4 c, const float4 g) {
  const v2f glo = (v2f){g.x, g.y}, ghi = (v2f){g.z, g.w};
  U13 = pkfma(c.x, glo, U13); U42 = pkfma(c.y, glo, U42);
  V13 = pkfma(c.z, ghi, V13); V42 = pkfma(c.w, ghi, V42);
}

__device__ inline unsigned short f2bf(float f) {
  __hip_bfloat16 h = __float2bfloat16(f);
  union { __hip_bfloat16 hh; unsigned short u; } cv;
  cv.hh = h;
  return cv.u;
}

// cw[row*K+k] = (c1r,c1i,c2r,c2i); cw[4K + row*K+k] = (c2r,c2i,c1r,c1i)
__global__ void prep_c_kernel(const float* __restrict__ c1r, const float* __restrict__ c1i,
                              const float* __restrict__ c2r, const float* __restrict__ c2i,
                              float4* __restrict__ cw) {
  int idx = blockIdx.x * blockDim.x + threadIdx.x;
  if (idx < 4 * KTAPS) {
    cw[idx]             = make_float4(c1r[idx], c1i[idx], c2r[idx], c2i[idx]);
    cw[4 * KTAPS + idx] = make_float4(c2r[idx], c2i[idx], c1r[idx], c1i[idx]);
  }
}

__device__ inline float4 gh_entry(const float4 e, const float4 f,
                                  const float4 fm, const float4 em) {
  v2f G = (v2f){fm.w * e.w, fm.w * (-e.z)};
  G = pkfma(fm.x, (v2f){e.x, e.y}, G);
  G = pkfma(fm.y, (v2f){e.y, -e.x}, G);
  G = pkfma(fm.z, (v2f){e.z, e.w}, G);
  v2f H = (v2f){em.w * f.w, em.w * (-f.z)};
  H = pkfma(em.x, (v2f){f.x, f.y}, H);
  H = pkfma(em.y, (v2f){f.y, -f.x}, H);
  H = pkfma(em.z, (v2f){f.z, f.w}, H);
  return make_float4(G.x, G.y, H.x, H.y);
}

// Fully-unrolled FIR over taps T=2*NMAX+1 for outputs A (w=2tid), B (w+1)
// sharing gh loads. h0/h1 = hi/lo walk bases (array indices), cc = c row.
template<int NMAX>
__device__ inline void fir_core(const float4* __restrict__ hiArr,
                                const float4* __restrict__ loArr,
                                int h0, int h1,
                                const float4* __restrict__ cc,
                                v2f& aU13, v2f& aU42, v2f& aV13, v2f& aV42,
                                v2f& bU13, v2f& bU42, v2f& bV13, v2f& bV42)
{
  float4 cOdd;
  {
    const float4 hi = hiArr[h0], lo = loArr[h1];
    const float4 c0 = cc[0], c1 = cc[1];
    mac(bU13, bU42, bV13, bV42, c0, hi);
    mac(bU13, bU42, bV13, bV42, c1, lo);
    mac(aU13, aU42, aV13, aV42, c0, lo);
    cOdd = c1;
  }
#pragma unroll
  for (int s = 1; s < NMAX; ++s) {
    const float4 hi = hiArr[h0 - s], lo = loArr[h1 - s];
    const float4 c2 = cc[2*s], c3 = cc[2*s + 1];
    mac(bU13, bU42, bV13, bV42, c2, hi);
    mac(bU13, bU42, bV13, bV42, c3, lo);
    mac(aU13, aU42, aV13, aV42, cOdd, hi);
    mac(aU13, aU42, aV13, aV42, c2, lo);
    cOdd = c3;
  }
  {
    const float4 hi = hiArr[h0 - NMAX], lo = loArr[h1 - NMAX];
    const float4 c2 = cc[2*NMAX];
    mac(bU13, bU42, bV13, bV42, c2, hi);
    mac(aU13, aU42, aV13, aV42, cOdd, hi);
    mac(aU13, aU42, aV13, aV42, c2, lo);
  }
}

#define FIR_SWITCH(NMX, HI, LO, H0, H1, CC) \
  switch (NMX) { \
    case 25: fir_core<25>(HI, LO, H0, H1, CC, U13a,U42a,V13a,V42a, U13b,U42b,V13b,V42b); break; \
    case 12: fir_core<12>(HI, LO, H0, H1, CC, U13a,U42a,V13a,V42a, U13b,U42b,V13b,V42b); break; \
    case  8: fir_core< 8>(HI, LO, H0, H1, CC, U13a,U42a,V13a,V42a, U13b,U42b,V13b,V42b); break; \
    case  6: fir_core< 6>(HI, LO, H0, H1, CC, U13a,U42a,V13a,V42a, U13b,U42b,V13b,V42b); break; \
    case  5: fir_core< 5>(HI, LO, H0, H1, CC, U13a,U42a,V13a,V42a, U13b,U42b,V13b,V42b); break; \
    case  4: fir_core< 4>(HI, LO, H0, H1, CC, U13a,U42a,V13a,V42a, U13b,U42b,V13b,V42b); break; \
    case  3: fir_core< 3>(HI, LO, H0, H1, CC, U13a,U42a,V13a,V42a, U13b,U42b,V13b,V42b); break; \
    case  2: fir_core< 2>(HI, LO, H0, H1, CC, U13a,U42a,V13a,V42a, U13b,U42b,V13b,V42b); break; \
    default: fir_core< 1>(HI, LO, H0, H1, CC, U13a,U42a,V13a,V42a, U13b,U42b,V13b,V42b); break; \
  }

__global__ __launch_bounds__(THREADS, 4) void hpbc_kernel(
    const float2* __restrict__ er, const float2* __restrict__ ei,
    const float2* __restrict__ fr, const float2* __restrict__ fi,
    const float*  __restrict__ task, const float4* __restrict__ cw,
    unsigned short* __restrict__ out, int nout, int lpad, int ntiles)
{
  __shared__ float4 sE[WIN];
  __shared__ float4 sF[WIN];
  __shared__ float4 ghE0[GHH], ghO0[GHH];
  __shared__ float4 ghE1[GHH], ghO1[GHH];

  const int bx   = blockIdx.x;
  const int b    = bx / ntiles;
  const int tile = bx - b * ntiles;
  const int tid  = threadIdx.x;
  const int i0   = lpad + tile * TILE;
  const int elo  = i0 - 2 * NM;

  const float2* erb = er + (size_t)b * NSEQ;
  const float2* eib = ei + (size_t)b * NSEQ;
  const float2* frb = fr + (size_t)b * NSEQ;
  const float2* fib = fi + (size_t)b * NSEQ;

  for (int u = tid; u < WIN; u += THREADS) {
    int g = (elo + u) & (NSEQ - 1);                  // exact jnp.roll wrap
    float2 a = erb[g], c = eib[g];
    sE[u] = make_float4(a.x, c.x, a.y, c.y);
    float2 d = frb[g], e = fib[g];
    sF[u] = make_float4(d.x, e.x, d.y, e.y);
  }

  const float dbm = task[b * 4 + 0];
  const float fsr = task[b * 4 + 2];
  const int   x   = (int)(fsr / 2.0e9f);
  const int ind = (x == 40) ? 1 : (x == 80) ? 2 : (x == 160) ? 3 : 0;
  const float4* __restrict__ crow = cw + ind * KTAPS;
  const float4* __restrict__ cswp = cw + 4 * KTAPS + ind * KTAPS;
  const float P  = powf(10.0f, dbm * 0.1f) * 0.5f;
  const float pf = P * sqrtf(P);

  __syncthreads();

  // Unshifted E/F for this thread's gh entries (bi = tid, tid+256, tid+512).
  const float4 e0 = sE[tid + NM],            f0 = sF[tid + NM];
  const float4 e1 = sE[tid + THREADS + NM],  f1 = sF[tid + THREADS + NM];
  const bool  has3 = (tid < GHW - 2 * THREADS);   // tid < 51
  float4 e2 = make_float4(0,0,0,0), f2 = e2;
  if (has3) { e2 = sE[tid + 2*THREADS + NM]; f2 = sF[tid + 2*THREADS + NM]; }

  // write GH of order Mn: entry bi reads sF/sE at [bi + (NM - Mn)].
  auto write_gh = [&](float4* wE, float4* wO, int Mn) {
    const int s = NM - Mn;
    const float4 g0 = gh_entry(e0, f0, sF[tid + s], sE[tid + s]);
    if (tid & 1) wO[tid >> 1] = g0; else wE[tid >> 1] = g0;
    const float4 g1 = gh_entry(e1, f1, sF[tid + THREADS + s], sE[tid + THREADS + s]);
    if (tid & 1) wO[(tid + THREADS) >> 1] = g1; else wE[(tid + THREADS) >> 1] = g1;
    if (has3) {
      const float4 g2 = gh_entry(e2, f2, sF[tid + 2*THREADS + s], sE[tid + 2*THREADS + s]);
      if (tid & 1) wO[(tid + 2*THREADS) >> 1] = g2; else wE[(tid + 2*THREADS) >> 1] = g2;
    }
  };

  v2f A0 = {0,0}, A1 = {0,0}, B0 = {0,0}, B1 = {0,0};
  int kbaseP = 199;          // +m rows: m=0 at 199, ascending
  int kbaseN = 199;          // -m rows: row -M starts at kbaseN - T(M)
  // Carries: eb_plus(0) and ea_minus(1) are both sE[2tid+51].
  float4 carry_p = sE[2*tid + 2*NM + 1];
  float4 carry_m = carry_p;

  auto iter = [&](const float4* rE, const float4* rO,
                  float4* wE, float4* wO, int M) {
    const int nmax = (M == 0) ? NM : (NM / M);
    const int T    = 2 * nmax + 1;

    // ---- FIR(+M): standard reduction ----
    {
      const int q = nmax & 1;
      const float4* hiArr = q ? rO : rE;
      const float4* loArr = q ? rE : rO;
      const int h0 = tid + ((26 + nmax) >> 1);
      const int h1 = tid + ((25 + nmax) >> 1);
      const float4* cc = crow + kbaseP;
      v2f U13a={0,0},U42a={0,0},V13a={0,0},V42a={0,0};
      v2f U13b={0,0},U42b={0,0},V13b={0,0},V42b={0,0};
      FIR_SWITCH(nmax, hiArr, loArr, h0, h1, cc);
      const float sra = U13a.x - U42a.y + V13a.x - V42a.y;
      const float sia = U13a.y + U42a.x + V13a.y + V42a.x;
      const float srb = U13b.x - U42b.y + V13b.x - V42b.y;
      const float sib = U13b.y + U42b.x + V13b.y + V42b.x;
      const float4 ea = sE[2*tid + 2*NM - M];    // E[i-M]
      const float4 eb = carry_p;                 // E[i+1-M] = prev ea
      carry_p = ea;
      A0 = pkfma(sra, (v2f){ea.x, ea.y}, pkfma(sia, (v2f){-ea.y, ea.x}, A0));
      A1 = pkfma(sra, (v2f){ea.z, ea.w}, pkfma(sia, (v2f){-ea.w, ea.z}, A1));
      B0 = pkfma(srb, (v2f){eb.x, eb.y}, pkfma(sib, (v2f){-eb.y, eb.x}, B0));
      B1 = pkfma(srb, (v2f){eb.z, eb.w}, pkfma(sib, (v2f){-eb.w, eb.z}, B1));
    }
    kbaseP += T;

    // ---- FIR(-M): same buffer, base shifted +M, swapped-c + conj reduction ----
    if (M > 0) {
      kbaseN -= T;
      const int qm = (M + nmax) & 1;
      const float4* hiArr = qm ? rO : rE;
      const float4* loArr = qm ? rE : rO;
      const int h0 = tid + ((26 + M + nmax) >> 1);
      const int h1 = tid + ((25 + M + nmax) >> 1);
      const float4* cc = cswp + kbaseN;
      v2f U13a={0,0},U42a={0,0},V13a={0,0},V42a={0,0};
      v2f U13b={0,0},U42b={0,0},V13b={0,0},V42b={0,0};
      FIR_SWITCH(nmax, hiArr, loArr, h0, h1, cc);
      // T = c1*conj(H) + c2*conj(G) with swapped-c macs:
      const float sra = U13a.x + U42a.y + V13a.x + V42a.y;
      const float sia = U42a.x - U13a.y + V42a.x - V13a.y;
      const float srb = U13b.x + U42b.y + V13b.x + V42b.y;
      const float sib = U42b.x - U13b.y + V42b.x - V13b.y;
      const float4 ea = carry_m;                       // E[i+M] = prev eb_minus
      const float4 eb = sE[2*tid + 2*NM + 1 + M];      // E[i+1+M]
      carry_m = eb;
      A0 = pkfma(sra, (v2f){ea.x, ea.y}, pkfma(sia, (v2f){-ea.y, ea.x}, A0));
      A1 = pkfma(sra, (v2f){ea.z, ea.w}, pkfma(sia, (v2f){-ea.w, ea.z}, A1));
      B0 = pkfma(srb, (v2f){eb.x, eb.y}, pkfma(sib, (v2f){-eb.y, eb.x}, B0));
      B1 = pkfma(srb, (v2f){eb.z, eb.w}, pkfma(sib, (v2f){-eb.w, eb.z}, B1));
    }

    // ---- GH(|m|=M+1) into the other buffer ----
    if (M < NM) write_gh(wE, wO, M + 1);

    __syncthreads();
  };

  // Prologue: GH(0) into buffer 0.
  write_gh(ghE0, ghO0, 0);
  __syncthreads();

  for (int M = 0; M <= NM; M += 2) {
    iter(ghE0, ghO0, ghE1, ghO1, M);           // even M: read buf0, write buf1
    if (M + 1 <= NM)
      iter(ghE1, ghO1, ghE0, ghO0, M + 1);     // odd M: read buf1, write buf0
  }

  // ---- Epilogue: (IMAG, REAL) element order ----
  const int end = lpad + nout;
  const size_t chunk1 = (size_t)BATCH * nout * 4;
  const int i = i0 + 2 * tid;
  if (i + 1 < end) {
    const float4 evA = sE[2*tid + 2*NM],     fvA = sF[2*tid + 2*NM];
    const float4 evB = sE[2*tid + 1 + 2*NM], fvB = sF[2*tid + 1 + 2*NM];
    const size_t o = ((size_t)b * nout + (size_t)(i - lpad)) * 4;
    ushort4 w0a, w0b, w1a, w1b;
    w0a.x = f2bf(evA.y); w0a.y = f2bf(evA.x); w0a.z = f2bf(evA.w); w0a.w = f2bf(evA.z);
    w0b.x = f2bf(evB.y); w0b.y = f2bf(evB.x); w0b.z = f2bf(evB.w); w0b.w = f2bf(evB.z);
    w1a.x = f2bf(fvA.y + pf * A0.y); w1a.y = f2bf(fvA.x + pf * A0.x);
    w1a.z = f2bf(fvA.w + pf * A1.y); w1a.w = f2bf(fvA.z + pf * A1.x);
    w1b.x = f2bf(fvB.y + pf * B0.y); w1b.y = f2bf(fvB.x + pf * B0.x);
    w1b.z = f2bf(fvB.w + pf * B1.y); w1b.w = f2bf(fvB.z + pf * B1.x);
    *reinterpret_cast<ushort4*>(out + o) = w0a;
    *reinterpret_cast<ushort4*>(out + o + 4) = w0b;
    *reinterpret_cast<ushort4*>(out + chunk1 + o) = w1a;
    *reinterpret_cast<ushort4*>(out + chunk1 + o + 4) = w1b;
  } else if (i < end) {
    const float4 evA = sE[2*tid + 2*NM], fvA = sF[2*tid + 2*NM];
    const size_t o = ((size_t)b * nout + (size_t)(i - lpad)) * 4;
    ushort4 w0a, w1a;
    w0a.x = f2bf(evA.y); w0a.y = f2bf(evA.x); w0a.z = f2bf(evA.w); w0a.w = f2bf(evA.z);
    w1a.x = f2bf(fvA.y + pf * A0.y); w1a.y = f2bf(fvA.x + pf * A0.x);
    w1a.z = f2bf(fvA.w + pf * A1.y); w1a.w = f2bf(fvA.z + pf * A1.x);
    *reinterpret_cast<ushort4*>(out + o) = w0a;
    *reinterpret_cast<ushort4*>(out + chunk1 + o) = w1a;
  }
}

} // namespace

extern "C" void kernel_launch(void* const* d_in, const int* in_sizes, int n_in,
                              void* d_out, int out_size, void* d_ws, size_t ws_size,
                              hipStream_t stream) {
  const float* E_real  = (const float*)d_in[0];
  const float* E_imag  = (const float*)d_in[1];
  const float* F_real  = (const float*)d_in[2];
  const float* F_imag  = (const float*)d_in[3];
  const float* C1_real = (const float*)d_in[4];
  const float* C1_imag = (const float*)d_in[5];
  const float* C2_real = (const float*)d_in[6];
  const float* C2_imag = (const float*)d_in[7];
  const float* task    = (const float*)d_in[8];

  int nout = out_size / 32;
  if (nout < 1 || nout > NSEQ) nout = NSEQ - 100;
  const int lpad   = (NSEQ - nout) / 2;             // 50
  const int ntiles = (nout + TILE - 1) / TILE;      // 128

  unsigned short* outp = (unsigned short*)d_out;
  float4* cw = (float4*)d_ws;                       // 2 tables: 57,472 B

  hipLaunchKernelGGL(prep_c_kernel, dim3((4 * KTAPS + 255) / 256), dim3(256), 0, stream,
                     C1_real, C1_imag, C2_real, C2_imag, cw);

  hipLaunchKernelGGL(hpbc_kernel, dim3(BATCH * ntiles), dim3(THREADS), 0, stream,
                     (const float2*)E_real, (const float2*)E_imag,
                     (const float2*)F_real, (const float2*)F_imag,
                     task, cw, outp, nout, lpad, ntiles);
}